// Round 1
// baseline (188.692 us; speedup 1.0000x reference)
//
#include <hip/hip_runtime.h>
#include <hip/hip_bf16.h>
#include <cstdint>

typedef unsigned short ushort_t;
typedef __bf16 bf16x8 __attribute__((ext_vector_type(8)));
typedef float f32x4 __attribute__((ext_vector_type(4)));

#define B_   16
#define S_   512
#define D_   768
#define E_   128
#define R_   2048
#define NREL 32768

__device__ inline ushort_t f2b(float f) {
    uint32_t u = __builtin_bit_cast(uint32_t, f);
    uint32_t r = (u + 0x7fffu + ((u >> 16) & 1u)) >> 16;   // RNE
    return (ushort_t)r;
}
__device__ inline float b2f(ushort_t u) {
    uint32_t v = ((uint32_t)u) << 16;
    return __builtin_bit_cast(float, v);
}
__device__ inline float bl(uint32_t u) {
    uint32_t v = u << 16;
    return __builtin_bit_cast(float, v);
}
__device__ inline float bh(uint32_t u) {
    uint32_t v = u & 0xffff0000u;
    return __builtin_bit_cast(float, v);
}

// ---------------------------------------------------------------------------
// Prep: coalesced float4 gather of entity hidden rows -> bf16 (emb half of
// the concat is folded into the per-label bias table biasE, so repE is only
// [2048,768] now), plus tiny tails (BmatT rows 768/769 from lW-head, lWtT,
// loss-slot zero).
// ---------------------------------------------------------------------------
__global__ __launch_bounds__(256) void prep_kernel(
    const float* __restrict__ hidden, const float* __restrict__ lW,
    const int* __restrict__ ent_start,
    ushort_t* __restrict__ repE, ushort_t* __restrict__ BmatT,
    ushort_t* __restrict__ lWtT, float* __restrict__ out)
{
    int idx = blockIdx.x * 256 + threadIdx.x;
    if (idx == 0) out[0] = 0.0f;
    if (idx < 393216) {                      // repE [2048,768] via float4
        int row = idx / 192, q = idx - row * 192;
        int c = q * 4;
        int b = row >> 7;
        int st = ent_start[row];
        const float* srcp = hidden + ((size_t)(b * S_ + st) * D_ + c);
        float4 v = *reinterpret_cast<const float4*>(srcp);
        uint32_t lo = (uint32_t)f2b(v.x) | ((uint32_t)f2b(v.y) << 16);
        uint32_t hi = (uint32_t)f2b(v.z) | ((uint32_t)f2b(v.w) << 16);
        uint2 pk; pk.x = lo; pk.y = hi;
        *reinterpret_cast<uint2*>(repE + (size_t)idx * 4) = pk;
        return;
    }
    int i2 = idx - 393216;
    if (i2 < 768) {                          // BmatT rows 768/769 (head-linear)
        int o = i2 / 384, kk = i2 - o * 384;
        BmatT[(768 + o) * 384 + kk] = f2b(lW[kk * 2 + o]);
        return;
    }
    i2 -= 768;
    if (i2 < 768) {                          // lWtT [2,384] (tail-linear)
        int o = i2 / 384, ii = i2 - o * 384;
        lWtT[o * 384 + ii] = f2b(lW[(384 + ii) * 2 + o]);
    }
}

// ---------------------------------------------------------------------------
// z<6: coalesced 32x32 LDS-tile transpose fp32 -> bf16 (W1 only top half now).
// z=6/7: biasE[l] = b1 + emb[l] @ W1_bottom  (fp32, the folded emb-half of
//        the tower-1 concat GEMM; 12 blocks x 4 k-chunks, LDS reduce).
// ---------------------------------------------------------------------------
__global__ __launch_bounds__(256) void transpose_w(
    const float* __restrict__ hW1, const float* __restrict__ tW1,
    const float* __restrict__ hW2, const float* __restrict__ tW2,
    const float* __restrict__ bil, const float* __restrict__ emb,
    const float* __restrict__ hb1, const float* __restrict__ tb1,
    ushort_t* __restrict__ hW1T, ushort_t* __restrict__ tW1T,
    ushort_t* __restrict__ hW2T, ushort_t* __restrict__ tW2T,
    ushort_t* __restrict__ BmatT,
    float* __restrict__ biasEh, float* __restrict__ biasEt)
{
    __shared__ float smem[1056];
    int z = blockIdx.z;
    if (z >= 6) {                            // biasE path
        if (blockIdx.y || blockIdx.x >= 12) return;
        const float* W1 = (z == 6) ? hW1 : tW1;
        const float* b1 = (z == 6) ? hb1 : tb1;
        float* dstB     = (z == 6) ? biasEh : biasEt;
        int c64 = threadIdx.x & 63, kc = threadIdx.x >> 6;
        int col = blockIdx.x * 64 + c64;
        float a0 = 0.f, a1 = 0.f, a2 = 0.f;
        const float* wp = W1 + (size_t)(768 + kc * 192) * 768 + col;
        const float* e0 = emb + kc * 192;
        for (int k = 0; k < 192; ++k) {
            float w = wp[(size_t)k * 768];
            a0 += e0[k] * w;
            a1 += e0[768 + k] * w;
            a2 += e0[1536 + k] * w;
        }
        smem[(kc * 3 + 0) * 64 + c64] = a0;
        smem[(kc * 3 + 1) * 64 + c64] = a1;
        smem[(kc * 3 + 2) * 64 + c64] = a2;
        __syncthreads();
        if (kc == 0) {
            float bv = b1[col];
#pragma unroll
            for (int l = 0; l < 3; ++l) {
                float s = smem[l * 64 + c64] + smem[(3 + l) * 64 + c64]
                        + smem[(6 + l) * 64 + c64] + smem[(9 + l) * 64 + c64];
                dstB[l * 768 + col] = bv + s;
            }
        }
        return;
    }
    const float* src; ushort_t* dst; int Rr, Cc;
    switch (z) {
        case 0:  src = hW1;          dst = hW1T;           Rr = 768; Cc = 768; break;
        case 1:  src = tW1;          dst = tW1T;           Rr = 768; Cc = 768; break;
        case 2:  src = hW2;          dst = hW2T;           Rr = 768; Cc = 384; break;
        case 3:  src = tW2;          dst = tW2T;           Rr = 768; Cc = 384; break;
        case 4:  src = bil;          dst = BmatT;          Rr = 384; Cc = 384; break;
        default: src = bil + 147456; dst = BmatT + 147456; Rr = 384; Cc = 384; break;
    }
    int tR = blockIdx.x * 32, tC = blockIdx.y * 32;
    if (tR >= Rr || tC >= Cc) return;
    int tx = threadIdx.x & 31, ty = threadIdx.x >> 5;     // ty in [0,8)
#pragma unroll
    for (int r = 0; r < 4; ++r)
        smem[(ty + r * 8) * 33 + tx] = src[(size_t)(tR + ty + r * 8) * Cc + tC + tx];
    __syncthreads();
#pragma unroll
    for (int r = 0; r < 4; ++r)
        dst[(size_t)(tC + ty + r * 8) * Rr + tR + tx] = f2b(smem[tx * 33 + ty + r * 8]);
}

// ---------------------------------------------------------------------------
// LDS-staged bf16 MFMA GEMM, 64x64 block tile (wave tile 32x32, BK=32).
// Small tiles on purpose: grids of 384-768 blocks give ~3 blocks/CU so other
// blocks' waves hide the vmcnt(0)+barrier drain (1 block/CU exposed it).
// A [M,K] row-major, Bt [N,K] row-major. blockIdx.z selects operand set
// (per-z N and f32-output flag; lab!=null selects per-row bias table mode).
// ---------------------------------------------------------------------------
__global__ __launch_bounds__(256) void gemm_lds(
    const ushort_t* __restrict__ A0, const ushort_t* __restrict__ A1,
    const ushort_t* __restrict__ Bt0, const ushort_t* __restrict__ Bt1,
    const float* __restrict__ bias0, const float* __restrict__ bias1,
    void* __restrict__ out0, void* __restrict__ out1,
    const int* __restrict__ lab,
    int M, int N0, int N1, int K, int doRelu, int f32o0, int f32o1)
{
    __shared__ ushort_t As[64 * 32];
    __shared__ ushort_t Bs[64 * 32];
    int N = blockIdx.z ? N1 : N0;
    int tileN = blockIdx.y * 64;
    if (tileN >= N) return;
    const ushort_t* A   = blockIdx.z ? A1 : A0;
    const ushort_t* Bt  = blockIdx.z ? Bt1 : Bt0;
    const float*   bias = blockIdx.z ? bias1 : bias0;
    int           f32o  = blockIdx.z ? f32o1 : f32o0;
    ushort_t*      outH = (ushort_t*)(blockIdx.z ? out1 : out0);
    float*         outF = (float*)(blockIdx.z ? out1 : out0);

    int t = threadIdx.x;
    int lane = t & 63, wave = t >> 6;
    int tileM = blockIdx.x * 64;
    int wm = (wave >> 1) * 32, wn = (wave & 1) * 32;
    int l15 = lane & 15, quad = lane >> 4;

    const ushort_t* gA = A  + (size_t)tileM * K;
    const ushort_t* gB = Bt + (size_t)tileN * K;

    // staging coords: 64 rows x 32 cols = 256 segments of 16B, one per thread
    int srow = t >> 2, sc8 = (t & 3) << 3;

    f32x4 acc[2][2];
#pragma unroll
    for (int a = 0; a < 2; ++a)
#pragma unroll
        for (int b = 0; b < 2; ++b) {
            acc[a][b][0] = 0.f; acc[a][b][1] = 0.f;
            acc[a][b][2] = 0.f; acc[a][b][3] = 0.f;
        }

    for (int k0 = 0; k0 < K; k0 += 32) {
        __builtin_amdgcn_global_load_lds(
            (const __attribute__((address_space(1))) void*)(gA + (size_t)srow * K + k0 + sc8),
            (__attribute__((address_space(3))) void*)(As + t * 8), 16, 0, 0);
        __builtin_amdgcn_global_load_lds(
            (const __attribute__((address_space(1))) void*)(gB + (size_t)srow * K + k0 + sc8),
            (__attribute__((address_space(3))) void*)(Bs + t * 8), 16, 0, 0);
        __syncthreads();
        bf16x8 af[2], bfr[2];
#pragma unroll
        for (int mi = 0; mi < 2; ++mi)
            af[mi] = *reinterpret_cast<const bf16x8*>(As + (wm + mi * 16 + l15) * 32 + quad * 8);
#pragma unroll
        for (int ni = 0; ni < 2; ++ni)
            bfr[ni] = *reinterpret_cast<const bf16x8*>(Bs + (wn + ni * 16 + l15) * 32 + quad * 8);
#pragma unroll
        for (int mi = 0; mi < 2; ++mi)
#pragma unroll
            for (int ni = 0; ni < 2; ++ni)
                acc[mi][ni] = __builtin_amdgcn_mfma_f32_16x16x32_bf16(af[mi], bfr[ni], acc[mi][ni], 0, 0, 0);
        __syncthreads();
    }

#pragma unroll
    for (int mi = 0; mi < 2; ++mi) {
        int gr = tileM + wm + mi * 16 + quad * 4;
        int lb4[4];
        if (lab) {
#pragma unroll
            for (int r = 0; r < 4; ++r) lb4[r] = lab[gr + r];
        }
#pragma unroll
        for (int ni = 0; ni < 2; ++ni) {
            int gc = tileN + wn + ni * 16 + l15;
            if (gc < N) {
#pragma unroll
                for (int r = 0; r < 4; ++r) {
                    float bb = lab ? bias[(size_t)lb4[r] * N + gc]
                                   : (bias ? bias[gc] : 0.0f);
                    float v = acc[mi][ni][r] + bb;
                    if (doRelu) v = fmaxf(v, 0.0f);
                    if (f32o) outF[(size_t)(gr + r) * N + gc] = v;
                    else      outH[(size_t)(gr + r) * N + gc] = f2b(v);
                }
            }
        }
    }
}

// ---------------------------------------------------------------------------
// Per-relation: logits + log-softmax + loss. One wave per 8 relations.
// Tail-linear term precomputed per ENTITY (tLin, f32) -> only 2 wave
// reductions per relation instead of 4, 3 loads per j-iter instead of 5.
// ---------------------------------------------------------------------------
__global__ __launch_bounds__(256) void rel_kernel(
    const ushort_t* __restrict__ Uext, const ushort_t* __restrict__ tailsE,
    const float* __restrict__ tLin, const float* __restrict__ lb,
    const int* __restrict__ rel_head, const int* __restrict__ rel_tail,
    const int* __restrict__ rel_label, float* __restrict__ out)
{
    __shared__ float wsum[4];
    int lane = threadIdx.x & 63, wave = threadIdx.x >> 6;
    float lb0 = lb[0], lb1 = lb[1];
    float lossAcc = 0.0f;
    int base = (blockIdx.x * 4 + wave) * 8;

    for (int q = 0; q < 8; ++q) {
        int rel = base + q;
        int b = rel >> 11;                    // R = 2048
        int h = rel_head[rel], t = rel_tail[rel], lab = rel_label[rel];
        const uint32_t* uh = reinterpret_cast<const uint32_t*>(Uext + (size_t)(b * E_ + h) * 770);
        const uint32_t* tv = reinterpret_cast<const uint32_t*>(tailsE + (size_t)(b * E_ + t) * 384);

        float a0 = 0.f, a1 = 0.f;
#pragma unroll
        for (int j = 0; j < 3; ++j) {
            int i = lane + 64 * j;
            uint32_t tu = tv[i];
            uint32_t u0 = uh[i], u1 = uh[192 + i];
            float tl = bl(tu), th = bh(tu);
            a0 += tl * bl(u0) + th * bh(u0);
            a1 += tl * bl(u1) + th * bh(u1);
        }
#pragma unroll
        for (int d = 1; d < 64; d <<= 1) {
            a0 += __shfl_xor(a0, d);
            a1 += __shfl_xor(a1, d);
        }
        const ushort_t* uhs = reinterpret_cast<const ushort_t*>(uh);
        float2 tp = reinterpret_cast<const float2*>(tLin)[b * E_ + t];
        float l0v = a0 + tp.x + b2f(uhs[768]) + lb0;
        float l1v = a1 + tp.y + b2f(uhs[769]) + lb1;
        if (lane == 0) {
            out[1 + 2 * rel]     = l0v;
            out[1 + 2 * rel + 1] = l1v;
        }
        float m = fmaxf(l0v, l1v);
        float lse = m + logf(expf(l0v - m) + expf(l1v - m));
        lossAcc += lse - (lab ? l1v : l0v);
    }
    if (lane == 0) wsum[wave] = lossAcc;
    __syncthreads();
    if (threadIdx.x == 0) {
        float s = wsum[0] + wsum[1] + wsum[2] + wsum[3];
        atomicAdd(out, s * (1.0f / 32768.0f));
    }
}

// ---------------------------------------------------------------------------
extern "C" void kernel_launch(void* const* d_in, const int* in_sizes, int n_in,
                              void* d_out, int out_size, void* d_ws, size_t ws_size,
                              hipStream_t stream)
{
    const float* hidden = (const float*)d_in[0];
    const float* emb    = (const float*)d_in[1];
    const float* hW1    = (const float*)d_in[2];
    const float* hb1    = (const float*)d_in[3];
    const float* hW2    = (const float*)d_in[4];
    const float* hb2    = (const float*)d_in[5];
    const float* tW1    = (const float*)d_in[6];
    const float* tb1    = (const float*)d_in[7];
    const float* tW2    = (const float*)d_in[8];
    const float* tb2    = (const float*)d_in[9];
    const float* bil    = (const float*)d_in[10];
    const float* lW     = (const float*)d_in[11];
    const float* lb     = (const float*)d_in[12];
    const int* ent_start = (const int*)d_in[13];
    const int* ent_label = (const int*)d_in[14];
    const int* rel_head  = (const int*)d_in[15];
    const int* rel_tail  = (const int*)d_in[16];
    const int* rel_label = (const int*)d_in[17];
    float* out = (float*)d_out;

    char* ws = (char*)d_ws;
    ushort_t* repE   = (ushort_t*)(ws + 0);         // [2048,768]
    ushort_t* hW1T   = (ushort_t*)(ws + 3145728);   // [768,768]  (top half only)
    ushort_t* tW1T   = (ushort_t*)(ws + 4325376);   // [768,768]
    ushort_t* hW2T   = (ushort_t*)(ws + 5505024);   // [384,768]
    ushort_t* tW2T   = (ushort_t*)(ws + 6094848);   // [384,768]
    ushort_t* BmatT  = (ushort_t*)(ws + 6684672);   // [770,384]
    ushort_t* lWtT   = (ushort_t*)(ws + 7276032);   // [2,384]
    float*    biasEh = (float*)   (ws + 7277568);   // [3,768] f32
    float*    biasEt = (float*)   (ws + 7286784);   // [3,768] f32
    float*    tLin   = (float*)   (ws + 7296000);   // [2048,2] f32
    ushort_t* h1     = (ushort_t*)(ws + 7312384);   // [2048,768]
    ushort_t* t1     = (ushort_t*)(ws + 10458112);  // [2048,768]
    ushort_t* headsE = (ushort_t*)(ws + 13603840);  // [2048,384]
    ushort_t* tailsE = (ushort_t*)(ws + 15176704);  // [2048,384]
    ushort_t* Uext   = (ushort_t*)(ws + 16749568);  // [2048,770]

    prep_kernel<<<1542, 256, 0, stream>>>(
        hidden, lW, ent_start, repE, BmatT, lWtT, out);

    transpose_w<<<dim3(24, 24, 8), 256, 0, stream>>>(
        hW1, tW1, hW2, tW2, bil, emb, hb1, tb1,
        hW1T, tW1T, hW2T, tW2T, BmatT, biasEh, biasEt);

    // tower-1: h1/t1 = relu(hid @ W1_top + biasE[lab])   (K halved 1536->768)
    gemm_lds<<<dim3(32, 12, 2), 256, 0, stream>>>(
        repE, repE, hW1T, tW1T, biasEh, biasEt, h1, t1, ent_label,
        2048, 768, 768, 768, 1, 0, 0);

    // tower-2: heads/tails = relu(h @ W2 + b2)
    gemm_lds<<<dim3(32, 6, 2), 256, 0, stream>>>(
        h1, t1, hW2T, tW2T, hb2, tb2, headsE, tailsE, nullptr,
        2048, 384, 384, 768, 1, 0, 0);

    // z=0: Uext = heads @ [bil0^T | bil1^T | lW_head]  (bf16)
    // z=1: tLin = tails @ lW_tail^T                    (f32, [2048,2])
    gemm_lds<<<dim3(32, 13, 2), 256, 0, stream>>>(
        headsE, tailsE, BmatT, lWtT, nullptr, nullptr, Uext, tLin, nullptr,
        2048, 770, 2, 384, 0, 0, 1);

    rel_kernel<<<1024, 256, 0, stream>>>(
        Uext, tailsE, tLin, lb, rel_head, rel_tail, rel_label, out);
}

// Round 2
// 175.324 us; speedup vs baseline: 1.0762x; 1.0762x over previous
//
#include <hip/hip_runtime.h>
#include <hip/hip_bf16.h>
#include <cstdint>

typedef unsigned short ushort_t;
typedef __bf16 bf16x8 __attribute__((ext_vector_type(8)));
typedef float f32x4 __attribute__((ext_vector_type(4)));

#define B_   16
#define S_   512
#define D_   768
#define E_   128
#define R_   2048
#define NREL 32768

__device__ inline ushort_t f2b(float f) {
    uint32_t u = __builtin_bit_cast(uint32_t, f);
    uint32_t r = (u + 0x7fffu + ((u >> 16) & 1u)) >> 16;   // RNE
    return (ushort_t)r;
}
__device__ inline float b2f(ushort_t u) {
    uint32_t v = ((uint32_t)u) << 16;
    return __builtin_bit_cast(float, v);
}
__device__ inline float bl(uint32_t u) {
    uint32_t v = u << 16;
    return __builtin_bit_cast(float, v);
}
__device__ inline float bh(uint32_t u) {
    uint32_t v = u & 0xffff0000u;
    return __builtin_bit_cast(float, v);
}

// ---------------------------------------------------------------------------
// Prep: coalesced float4 gather of entity hidden rows -> bf16, tiny tails
// (BmatT rows 768/769, lWtT), zero loss slot and biasE tables (so the next
// dispatch can atomicAdd into them -- stream order guarantees the zeroes land
// first).
// ---------------------------------------------------------------------------
__global__ __launch_bounds__(256) void prep_kernel(
    const float* __restrict__ hidden, const float* __restrict__ lW,
    const int* __restrict__ ent_start,
    ushort_t* __restrict__ repE, ushort_t* __restrict__ BmatT,
    ushort_t* __restrict__ lWtT, float* __restrict__ biasEh,
    float* __restrict__ out)
{
    int idx = blockIdx.x * 256 + threadIdx.x;
    if (idx == 0) out[0] = 0.0f;
    if (idx < 393216) {                      // repE [2048,768] via float4
        int row = idx / 192, q = idx - row * 192;
        int c = q * 4;
        int b = row >> 7;
        int st = ent_start[row];
        const float* srcp = hidden + ((size_t)(b * S_ + st) * D_ + c);
        float4 v = *reinterpret_cast<const float4*>(srcp);
        uint32_t lo = (uint32_t)f2b(v.x) | ((uint32_t)f2b(v.y) << 16);
        uint32_t hi = (uint32_t)f2b(v.z) | ((uint32_t)f2b(v.w) << 16);
        uint2 pk; pk.x = lo; pk.y = hi;
        *reinterpret_cast<uint2*>(repE + (size_t)idx * 4) = pk;
        return;
    }
    int i2 = idx - 393216;
    if (i2 < 768) {                          // BmatT rows 768/769 (head-linear)
        int o = i2 / 384, kk = i2 - o * 384;
        BmatT[(768 + o) * 384 + kk] = f2b(lW[kk * 2 + o]);
        return;
    }
    i2 -= 768;
    if (i2 < 768) {                          // lWtT [2,384] (tail-linear)
        int o = i2 / 384, ii = i2 - o * 384;
        lWtT[o * 384 + ii] = f2b(lW[(384 + ii) * 2 + o]);
        return;
    }
    i2 -= 768;
    if (i2 < 4608) biasEh[i2] = 0.0f;        // biasEh+biasEt contiguous [2][3][768]
}

// ---------------------------------------------------------------------------
// z<6: coalesced 32x32 LDS-tile transpose fp32 -> bf16 (W1 top half only).
// z=6/7: biasE[l] = b1 + emb[l] @ W1_bottom, k-split 16 ways x 12 col-blocks
//        (384 blocks/tower) with LDS partial reduce + atomicAdd. Fixes the
//        round-1 regression: 24-block serial version was a ~8us cold-HBM
//        latency straggler on the critical path before GEMM1.
// ---------------------------------------------------------------------------
__global__ __launch_bounds__(256) void transpose_w(
    const float* __restrict__ hW1, const float* __restrict__ tW1,
    const float* __restrict__ hW2, const float* __restrict__ tW2,
    const float* __restrict__ bil, const float* __restrict__ emb,
    const float* __restrict__ hb1, const float* __restrict__ tb1,
    ushort_t* __restrict__ hW1T, ushort_t* __restrict__ tW1T,
    ushort_t* __restrict__ hW2T, ushort_t* __restrict__ tW2T,
    ushort_t* __restrict__ BmatT,
    float* __restrict__ biasEh, float* __restrict__ biasEt)
{
    __shared__ float smem[1056];
    int z = blockIdx.z;
    if (z >= 6) {                            // biasE path, 12 x 16 blocks
        int bx = blockIdx.x, by = blockIdx.y;
        if (bx >= 12 || by >= 16) return;
        const float* W1 = (z == 6) ? hW1 : tW1;
        const float* b1 = (z == 6) ? hb1 : tb1;
        float* dstB     = (z == 6) ? biasEh : biasEt;
        int c64 = threadIdx.x & 63, kg = threadIdx.x >> 6;   // kg in [0,4)
        int col = bx * 64 + c64;
        int k0r = by * 48 + kg * 12;
        const float* wp = W1 + (size_t)(768 + k0r) * 768 + col;
        const float* e0 = emb + k0r;
        float a0 = 0.f, a1 = 0.f, a2 = 0.f;
#pragma unroll
        for (int k = 0; k < 12; ++k) {
            float w = wp[(size_t)k * 768];
            a0 += e0[k] * w;
            a1 += e0[768 + k] * w;
            a2 += e0[1536 + k] * w;
        }
        smem[(kg * 3 + 0) * 64 + c64] = a0;
        smem[(kg * 3 + 1) * 64 + c64] = a1;
        smem[(kg * 3 + 2) * 64 + c64] = a2;
        __syncthreads();
        if (kg == 0) {
            float bv = (by == 0) ? b1[col] : 0.0f;
#pragma unroll
            for (int l = 0; l < 3; ++l) {
                float s = smem[l * 64 + c64] + smem[(3 + l) * 64 + c64]
                        + smem[(6 + l) * 64 + c64] + smem[(9 + l) * 64 + c64];
                atomicAdd(&dstB[l * 768 + col], bv + s);
            }
        }
        return;
    }
    const float* src; ushort_t* dst; int Rr, Cc;
    switch (z) {
        case 0:  src = hW1;          dst = hW1T;           Rr = 768; Cc = 768; break;
        case 1:  src = tW1;          dst = tW1T;           Rr = 768; Cc = 768; break;
        case 2:  src = hW2;          dst = hW2T;           Rr = 768; Cc = 384; break;
        case 3:  src = tW2;          dst = tW2T;           Rr = 768; Cc = 384; break;
        case 4:  src = bil;          dst = BmatT;          Rr = 384; Cc = 384; break;
        default: src = bil + 147456; dst = BmatT + 147456; Rr = 384; Cc = 384; break;
    }
    int tR = blockIdx.x * 32, tC = blockIdx.y * 32;
    if (tR >= Rr || tC >= Cc) return;
    int tx = threadIdx.x & 31, ty = threadIdx.x >> 5;     // ty in [0,8)
#pragma unroll
    for (int r = 0; r < 4; ++r)
        smem[(ty + r * 8) * 33 + tx] = src[(size_t)(tR + ty + r * 8) * Cc + tC + tx];
    __syncthreads();
#pragma unroll
    for (int r = 0; r < 4; ++r)
        dst[(size_t)(tC + ty + r * 8) * Rr + tR + tx] = f2b(smem[tx * 33 + ty + r * 8]);
}

// ---------------------------------------------------------------------------
// LDS-staged bf16 MFMA GEMM, 64x64 block tile (wave tile 32x32, BK=32).
// Round-2 structure: (a) XOR-swizzled LDS (16B seg ^= (row>>1)&3) applied on
// the per-lane GLOBAL source (global_load_lds dest must stay linear) and on
// the ds_read address -> conflict-free ds_read_b128 (was ~4-way); (b) 2-deep
// LDS double-buffer with ONE barrier per K-step: stage of tile k+1 is issued
// before the ds_read+MFMA of tile k; __syncthreads()'s implicit
// vmcnt(0)+lgkmcnt(0) drain makes the hand-off race-free.
// A [M,K] row-major, Bt [N,K] row-major. blockIdx.z selects operand set.
// ---------------------------------------------------------------------------
__global__ __launch_bounds__(256) void gemm_lds(
    const ushort_t* __restrict__ A0, const ushort_t* __restrict__ A1,
    const ushort_t* __restrict__ Bt0, const ushort_t* __restrict__ Bt1,
    const float* __restrict__ bias0, const float* __restrict__ bias1,
    void* __restrict__ out0, void* __restrict__ out1,
    const int* __restrict__ lab,
    int M, int N0, int N1, int K, int doRelu, int f32o0, int f32o1)
{
    __shared__ ushort_t As[2][2048];
    __shared__ ushort_t Bs[2][2048];
    int N = blockIdx.z ? N1 : N0;
    int tileN = blockIdx.y * 64;
    if (tileN >= N) return;
    const ushort_t* A   = blockIdx.z ? A1 : A0;
    const ushort_t* Bt  = blockIdx.z ? Bt1 : Bt0;
    const float*   bias = blockIdx.z ? bias1 : bias0;
    int           f32o  = blockIdx.z ? f32o1 : f32o0;
    ushort_t*      outH = (ushort_t*)(blockIdx.z ? out1 : out0);
    float*         outF = (float*)(blockIdx.z ? out1 : out0);

    int t = threadIdx.x;
    int lane = t & 63, wave = t >> 6;
    int tileM = blockIdx.x * 64;
    int wm = (wave >> 1) * 32, wn = (wave & 1) * 32;
    int l15 = lane & 15, quad = lane >> 4;

    // staging: 64 rows x 4 segs of 16B; LDS dest linear (t*16B), global
    // source segment XOR-swizzled so that LDS slot s holds seg s^((row>>1)&3)
    int srow = t >> 2;
    int sgl  = (((t & 3) ^ ((t >> 3) & 3)) << 3);          // ushort offset
    const ushort_t* pA = A  + (size_t)(tileM + srow) * K + sgl;
    const ushort_t* pB = Bt + (size_t)(tileN + srow) * K + sgl;
    int ldst = t * 8;                                      // ushort offset

    // swizzled ds_read offsets (row*32 + (quad^((row>>1)&3))*8 ushorts)
    int rA0 = wm + l15,      rA1 = wm + 16 + l15;
    int rB0 = wn + l15,      rB1 = wn + 16 + l15;
    int offA0 = rA0 * 32 + ((quad ^ ((rA0 >> 1) & 3)) << 3);
    int offA1 = rA1 * 32 + ((quad ^ ((rA1 >> 1) & 3)) << 3);
    int offB0 = rB0 * 32 + ((quad ^ ((rB0 >> 1) & 3)) << 3);
    int offB1 = rB1 * 32 + ((quad ^ ((rB1 >> 1) & 3)) << 3);

    f32x4 acc[2][2];
#pragma unroll
    for (int a = 0; a < 2; ++a)
#pragma unroll
        for (int b = 0; b < 2; ++b) {
            acc[a][b][0] = 0.f; acc[a][b][1] = 0.f;
            acc[a][b][2] = 0.f; acc[a][b][3] = 0.f;
        }

    // prologue: stage tile 0 into buffer 0
    __builtin_amdgcn_global_load_lds(
        (const __attribute__((address_space(1))) void*)pA,
        (__attribute__((address_space(3))) void*)(&As[0][ldst]), 16, 0, 0);
    __builtin_amdgcn_global_load_lds(
        (const __attribute__((address_space(1))) void*)pB,
        (__attribute__((address_space(3))) void*)(&Bs[0][ldst]), 16, 0, 0);
    __syncthreads();

    int nk = K >> 5;
    for (int kt = 0; kt < nk; ++kt) {
        int cur = kt & 1;
        if (kt + 1 < nk) {                   // issue next-tile stage early
            int ko = (kt + 1) << 5;
            __builtin_amdgcn_global_load_lds(
                (const __attribute__((address_space(1))) void*)(pA + ko),
                (__attribute__((address_space(3))) void*)(&As[cur ^ 1][ldst]), 16, 0, 0);
            __builtin_amdgcn_global_load_lds(
                (const __attribute__((address_space(1))) void*)(pB + ko),
                (__attribute__((address_space(3))) void*)(&Bs[cur ^ 1][ldst]), 16, 0, 0);
        }
        bf16x8 af0 = *reinterpret_cast<const bf16x8*>(&As[cur][offA0]);
        bf16x8 af1 = *reinterpret_cast<const bf16x8*>(&As[cur][offA1]);
        bf16x8 bf0 = *reinterpret_cast<const bf16x8*>(&Bs[cur][offB0]);
        bf16x8 bf1 = *reinterpret_cast<const bf16x8*>(&Bs[cur][offB1]);
        acc[0][0] = __builtin_amdgcn_mfma_f32_16x16x32_bf16(af0, bf0, acc[0][0], 0, 0, 0);
        acc[0][1] = __builtin_amdgcn_mfma_f32_16x16x32_bf16(af0, bf1, acc[0][1], 0, 0, 0);
        acc[1][0] = __builtin_amdgcn_mfma_f32_16x16x32_bf16(af1, bf0, acc[1][0], 0, 0, 0);
        acc[1][1] = __builtin_amdgcn_mfma_f32_16x16x32_bf16(af1, bf1, acc[1][1], 0, 0, 0);
        __syncthreads();                     // drains vmcnt+lgkmcnt: next tile ready,
    }                                        // current buffer fully consumed

#pragma unroll
    for (int mi = 0; mi < 2; ++mi) {
        int gr = tileM + wm + mi * 16 + quad * 4;
        int lb4[4];
        if (lab) {
#pragma unroll
            for (int r = 0; r < 4; ++r) lb4[r] = lab[gr + r];
        }
#pragma unroll
        for (int ni = 0; ni < 2; ++ni) {
            int gc = tileN + wn + ni * 16 + l15;
            if (gc < N) {
#pragma unroll
                for (int r = 0; r < 4; ++r) {
                    float bb = lab ? bias[(size_t)lb4[r] * N + gc]
                                   : (bias ? bias[gc] : 0.0f);
                    float v = acc[mi][ni][r] + bb;
                    if (doRelu) v = fmaxf(v, 0.0f);
                    if (f32o) outF[(size_t)(gr + r) * N + gc] = v;
                    else      outH[(size_t)(gr + r) * N + gc] = f2b(v);
                }
            }
        }
    }
}

// ---------------------------------------------------------------------------
// Per-relation: logits + log-softmax + loss. One wave per 8 relations.
// Tail-linear term precomputed per ENTITY (tLin, f32).
// ---------------------------------------------------------------------------
__global__ __launch_bounds__(256) void rel_kernel(
    const ushort_t* __restrict__ Uext, const ushort_t* __restrict__ tailsE,
    const float* __restrict__ tLin, const float* __restrict__ lb,
    const int* __restrict__ rel_head, const int* __restrict__ rel_tail,
    const int* __restrict__ rel_label, float* __restrict__ out)
{
    __shared__ float wsum[4];
    int lane = threadIdx.x & 63, wave = threadIdx.x >> 6;
    float lb0 = lb[0], lb1 = lb[1];
    float lossAcc = 0.0f;
    int base = (blockIdx.x * 4 + wave) * 8;

    for (int q = 0; q < 8; ++q) {
        int rel = base + q;
        int b = rel >> 11;                    // R = 2048
        int h = rel_head[rel], t = rel_tail[rel], lab = rel_label[rel];
        const uint32_t* uh = reinterpret_cast<const uint32_t*>(Uext + (size_t)(b * E_ + h) * 770);
        const uint32_t* tv = reinterpret_cast<const uint32_t*>(tailsE + (size_t)(b * E_ + t) * 384);

        float a0 = 0.f, a1 = 0.f;
#pragma unroll
        for (int j = 0; j < 3; ++j) {
            int i = lane + 64 * j;
            uint32_t tu = tv[i];
            uint32_t u0 = uh[i], u1 = uh[192 + i];
            float tl = bl(tu), th = bh(tu);
            a0 += tl * bl(u0) + th * bh(u0);
            a1 += tl * bl(u1) + th * bh(u1);
        }
#pragma unroll
        for (int d = 1; d < 64; d <<= 1) {
            a0 += __shfl_xor(a0, d);
            a1 += __shfl_xor(a1, d);
        }
        const ushort_t* uhs = reinterpret_cast<const ushort_t*>(uh);
        float2 tp = reinterpret_cast<const float2*>(tLin)[b * E_ + t];
        float l0v = a0 + tp.x + b2f(uhs[768]) + lb0;
        float l1v = a1 + tp.y + b2f(uhs[769]) + lb1;
        if (lane == 0) {
            out[1 + 2 * rel]     = l0v;
            out[1 + 2 * rel + 1] = l1v;
        }
        float m = fmaxf(l0v, l1v);
        float lse = m + logf(expf(l0v - m) + expf(l1v - m));
        lossAcc += lse - (lab ? l1v : l0v);
    }
    if (lane == 0) wsum[wave] = lossAcc;
    __syncthreads();
    if (threadIdx.x == 0) {
        float s = wsum[0] + wsum[1] + wsum[2] + wsum[3];
        atomicAdd(out, s * (1.0f / 32768.0f));
    }
}

// ---------------------------------------------------------------------------
extern "C" void kernel_launch(void* const* d_in, const int* in_sizes, int n_in,
                              void* d_out, int out_size, void* d_ws, size_t ws_size,
                              hipStream_t stream)
{
    const float* hidden = (const float*)d_in[0];
    const float* emb    = (const float*)d_in[1];
    const float* hW1    = (const float*)d_in[2];
    const float* hb1    = (const float*)d_in[3];
    const float* hW2    = (const float*)d_in[4];
    const float* hb2    = (const float*)d_in[5];
    const float* tW1    = (const float*)d_in[6];
    const float* tb1    = (const float*)d_in[7];
    const float* tW2    = (const float*)d_in[8];
    const float* tb2    = (const float*)d_in[9];
    const float* bil    = (const float*)d_in[10];
    const float* lW     = (const float*)d_in[11];
    const float* lb     = (const float*)d_in[12];
    const int* ent_start = (const int*)d_in[13];
    const int* ent_label = (const int*)d_in[14];
    const int* rel_head  = (const int*)d_in[15];
    const int* rel_tail  = (const int*)d_in[16];
    const int* rel_label = (const int*)d_in[17];
    float* out = (float*)d_out;

    char* ws = (char*)d_ws;
    ushort_t* repE   = (ushort_t*)(ws + 0);         // [2048,768]
    ushort_t* hW1T   = (ushort_t*)(ws + 3145728);   // [768,768]  (top half only)
    ushort_t* tW1T   = (ushort_t*)(ws + 4325376);   // [768,768]
    ushort_t* hW2T   = (ushort_t*)(ws + 5505024);   // [384,768]
    ushort_t* tW2T   = (ushort_t*)(ws + 6094848);   // [384,768]
    ushort_t* BmatT  = (ushort_t*)(ws + 6684672);   // [770,384]
    ushort_t* lWtT   = (ushort_t*)(ws + 7276032);   // [2,384]
    float*    biasEh = (float*)   (ws + 7277568);   // [3,768] f32
    float*    biasEt = (float*)   (ws + 7286784);   // [3,768] f32
    float*    tLin   = (float*)   (ws + 7296000);   // [2048,2] f32
    ushort_t* h1     = (ushort_t*)(ws + 7312384);   // [2048,768]
    ushort_t* t1     = (ushort_t*)(ws + 10458112);  // [2048,768]
    ushort_t* headsE = (ushort_t*)(ws + 13603840);  // [2048,384]
    ushort_t* tailsE = (ushort_t*)(ws + 15176704);  // [2048,384]
    ushort_t* Uext   = (ushort_t*)(ws + 16749568);  // [2048,770]

    prep_kernel<<<1560, 256, 0, stream>>>(
        hidden, lW, ent_start, repE, BmatT, lWtT, biasEh, out);

    transpose_w<<<dim3(24, 24, 8), 256, 0, stream>>>(
        hW1, tW1, hW2, tW2, bil, emb, hb1, tb1,
        hW1T, tW1T, hW2T, tW2T, BmatT, biasEh, biasEt);

    // tower-1: h1/t1 = relu(hid @ W1_top + biasE[lab])   (K halved 1536->768)
    gemm_lds<<<dim3(32, 12, 2), 256, 0, stream>>>(
        repE, repE, hW1T, tW1T, biasEh, biasEt, h1, t1, ent_label,
        2048, 768, 768, 768, 1, 0, 0);

    // tower-2: heads/tails = relu(h @ W2 + b2)
    gemm_lds<<<dim3(32, 6, 2), 256, 0, stream>>>(
        h1, t1, hW2T, tW2T, hb2, tb2, headsE, tailsE, nullptr,
        2048, 384, 384, 768, 1, 0, 0);

    // z=0: Uext = heads @ [bil0^T | bil1^T | lW_head]  (bf16)
    // z=1: tLin = tails @ lW_tail^T                    (f32, [2048,2])
    gemm_lds<<<dim3(32, 13, 2), 256, 0, stream>>>(
        headsE, tailsE, BmatT, lWtT, nullptr, nullptr, Uext, tLin, nullptr,
        2048, 770, 2, 384, 0, 0, 1);

    rel_kernel<<<1024, 256, 0, stream>>>(
        Uext, tailsE, tLin, lb, rel_head, rel_tail, rel_label, out);
}

// Round 4
// 173.627 us; speedup vs baseline: 1.0868x; 1.0098x over previous
//
#include <hip/hip_runtime.h>
#include <hip/hip_bf16.h>
#include <cstdint>

typedef unsigned short ushort_t;
typedef __bf16 bf16x8 __attribute__((ext_vector_type(8)));
typedef float f32x4 __attribute__((ext_vector_type(4)));

#define B_   16
#define S_   512
#define D_   768
#define E_   128
#define R_   2048
#define NREL 32768

__device__ inline ushort_t f2b(float f) {
    uint32_t u = __builtin_bit_cast(uint32_t, f);
    uint32_t r = (u + 0x7fffu + ((u >> 16) & 1u)) >> 16;   // RNE
    return (ushort_t)r;
}
__device__ inline float b2f(ushort_t u) {
    uint32_t v = ((uint32_t)u) << 16;
    return __builtin_bit_cast(float, v);
}
__device__ inline float bl(uint32_t u) {
    uint32_t v = u << 16;
    return __builtin_bit_cast(float, v);
}
__device__ inline float bh(uint32_t u) {
    uint32_t v = u & 0xffff0000u;
    return __builtin_bit_cast(float, v);
}

// ---------------------------------------------------------------------------
// Fused prep: one dispatch replaces prep_kernel + transpose_w.
// Block ranges (dispatch order -> biasE latency-stragglers start first):
//   [0,24):    biasE[l] = b1 + emb[l] @ W1_bottom (full-K per block)
//   [24,1566): repE float4 gather -> bf16, BmatT rows 768/769, lWtT, out[0]=0
//   [1566,3582): six 32x32-tiled fp32->bf16 transposes (W1-top, W2, bil)
// ---------------------------------------------------------------------------
#define NB_BIAS 24
#define NB_PREP 1542

__global__ __launch_bounds__(256) void prep_fused(
    const float* __restrict__ hidden, const float* __restrict__ emb,
    const float* __restrict__ lW,
    const float* __restrict__ hW1, const float* __restrict__ tW1,
    const float* __restrict__ hW2, const float* __restrict__ tW2,
    const float* __restrict__ bil,
    const float* __restrict__ hb1, const float* __restrict__ tb1,
    const int* __restrict__ ent_start,
    ushort_t* __restrict__ repE,
    ushort_t* __restrict__ hW1T, ushort_t* __restrict__ tW1T,
    ushort_t* __restrict__ hW2T, ushort_t* __restrict__ tW2T,
    ushort_t* __restrict__ BmatT, ushort_t* __restrict__ lWtT,
    float* __restrict__ biasEh, float* __restrict__ biasEt,
    float* __restrict__ out)
{
    __shared__ float smem[3072];
    int bid = blockIdx.x;
    int tid = threadIdx.x;

    if (bid < NB_BIAS) {
        // 12 col-blocks of 64 cols x 2 towers; 16 k-groups of 48 rows each.
        int tower = bid / 12, cb = bid - tower * 12;
        const float* W1 = tower ? tW1 : hW1;
        const float* b1 = tower ? tb1 : hb1;
        float* dstB     = tower ? biasEt : biasEh;
        int c4 = (tid & 15) * 4;              // col quad within the 64
        int kg = tid >> 4;                    // 16 k-groups
        int col0 = cb * 64;
        const float* wp = W1 + (size_t)(768 + kg * 48) * 768 + col0 + c4;
        const float* ep = emb + kg * 48;
        float a0x = 0.f, a0y = 0.f, a0z = 0.f, a0w = 0.f;
        float a1x = 0.f, a1y = 0.f, a1z = 0.f, a1w = 0.f;
        float a2x = 0.f, a2y = 0.f, a2z = 0.f, a2w = 0.f;
#pragma unroll 8
        for (int k = 0; k < 48; ++k) {
            float4 w = *reinterpret_cast<const float4*>(wp + (size_t)k * 768);
            float e0 = ep[k], e1 = ep[768 + k], e2 = ep[1536 + k];
            a0x += e0 * w.x; a0y += e0 * w.y; a0z += e0 * w.z; a0w += e0 * w.w;
            a1x += e1 * w.x; a1y += e1 * w.y; a1z += e1 * w.z; a1w += e1 * w.w;
            a2x += e2 * w.x; a2y += e2 * w.y; a2z += e2 * w.z; a2w += e2 * w.w;
        }
        smem[kg * 192 +   0 + c4 + 0] = a0x;
        smem[kg * 192 +   0 + c4 + 1] = a0y;
        smem[kg * 192 +   0 + c4 + 2] = a0z;
        smem[kg * 192 +   0 + c4 + 3] = a0w;
        smem[kg * 192 +  64 + c4 + 0] = a1x;
        smem[kg * 192 +  64 + c4 + 1] = a1y;
        smem[kg * 192 +  64 + c4 + 2] = a1z;
        smem[kg * 192 +  64 + c4 + 3] = a1w;
        smem[kg * 192 + 128 + c4 + 0] = a2x;
        smem[kg * 192 + 128 + c4 + 1] = a2y;
        smem[kg * 192 + 128 + c4 + 2] = a2z;
        smem[kg * 192 + 128 + c4 + 3] = a2w;
        __syncthreads();
        if (tid < 192) {
            int l = tid >> 6, c = tid & 63;
            float s = 0.f;
#pragma unroll
            for (int g = 0; g < 16; ++g) s += smem[g * 192 + l * 64 + c];
            dstB[l * 768 + col0 + c] = b1[col0 + c] + s;
        }
        return;
    }

    int pb = bid - NB_BIAS;
    if (pb < NB_PREP) {
        int idx = pb * 256 + tid;
        if (idx == 0) out[0] = 0.0f;
        if (idx < 393216) {                  // repE [2048,768] via float4
            int row = idx / 192, q = idx - row * 192;
            int c = q * 4;
            int b = row >> 7;
            int st = ent_start[row];
            const float* srcp = hidden + ((size_t)(b * S_ + st) * D_ + c);
            float4 v = *reinterpret_cast<const float4*>(srcp);
            uint32_t lo = (uint32_t)f2b(v.x) | ((uint32_t)f2b(v.y) << 16);
            uint32_t hi = (uint32_t)f2b(v.z) | ((uint32_t)f2b(v.w) << 16);
            uint2 pk; pk.x = lo; pk.y = hi;
            *reinterpret_cast<uint2*>(repE + (size_t)idx * 4) = pk;
            return;
        }
        int i2 = idx - 393216;
        if (i2 < 768) {                      // BmatT rows 768/769 (head-linear)
            int o = i2 / 384, kk = i2 - o * 384;
            BmatT[(768 + o) * 384 + kk] = f2b(lW[kk * 2 + o]);
            return;
        }
        i2 -= 768;
        if (i2 < 768) {                      // lWtT [2,384] (tail-linear)
            int o = i2 / 384, ii = i2 - o * 384;
            lWtT[o * 384 + ii] = f2b(lW[(384 + ii) * 2 + o]);
        }
        return;
    }

    int r = pb - NB_PREP;                    // transposes
    const float* src; ushort_t* dst; int Rr, Cc, xs;
    if (r < 576)        { src = hW1;          dst = hW1T;  Rr = 768; Cc = 768; xs = 24; }
    else if (r < 1152)  { r -= 576;  src = tW1;          dst = tW1T;  Rr = 768; Cc = 768; xs = 24; }
    else if (r < 1440)  { r -= 1152; src = hW2;          dst = hW2T;  Rr = 768; Cc = 384; xs = 24; }
    else if (r < 1728)  { r -= 1440; src = tW2;          dst = tW2T;  Rr = 768; Cc = 384; xs = 24; }
    else if (r < 1872)  { r -= 1728; src = bil;          dst = BmatT; Rr = 384; Cc = 384; xs = 12; }
    else                { r -= 1872; src = bil + 147456; dst = BmatT + 147456; Rr = 384; Cc = 384; xs = 12; }
    int bx = r % xs, by = r / xs;
    int tR = bx * 32, tC = by * 32;
    int tx = tid & 31, ty = tid >> 5;        // ty in [0,8)
#pragma unroll
    for (int rr = 0; rr < 4; ++rr)
        smem[(ty + rr * 8) * 33 + tx] = src[(size_t)(tR + ty + rr * 8) * Cc + tC + tx];
    __syncthreads();
#pragma unroll
    for (int rr = 0; rr < 4; ++rr)
        dst[(size_t)(tC + ty + rr * 8) * Rr + tR + tx] = f2b(smem[tx * 33 + ty + rr * 8]);
}

// ---------------------------------------------------------------------------
// LDS-staged bf16 MFMA GEMM, 64x64 block tile, BK=64, one barrier per K-step.
// ROUND-4 FIX: global_load_lds writes LDS at wave-uniform base + lane*16B
// (m104/m108) -- round-3 gave per-lane dests at 32B stride, which the HW
// ignores (half the tile stayed uninitialized -> NaN). Now each of the 2
// staging calls per matrix covers one contiguous lane*16 region per wave:
// call c stages LDS rows wave*16 + c*8 + (lane>>3), phys slot lane&7, with
// the global seg pre-swizzled: gseg = (lane&7) ^ (lane>>3)  (= phys ^ (row&7)
// since row&7 == lane>>3 here). ds_read side unchanged: logical seg s of row
// r lives at phys s^(r&7) -> conflict-free ds_read_b128 at 128-B row stride.
// 2-deep double buffer; __syncthreads()'s implicit vmcnt(0)+lgkmcnt(0) drain
// makes the hand-off race-free. A [M,K] row-major, Bt [N,K] row-major.
// blockIdx.z selects operand set.
// ---------------------------------------------------------------------------
#define GLL16(src, dst) __builtin_amdgcn_global_load_lds( \
    (const __attribute__((address_space(1))) void*)(src), \
    (__attribute__((address_space(3))) void*)(dst), 16, 0, 0)

__global__ __launch_bounds__(256) void gemm_lds(
    const ushort_t* __restrict__ A0, const ushort_t* __restrict__ A1,
    const ushort_t* __restrict__ Bt0, const ushort_t* __restrict__ Bt1,
    const float* __restrict__ bias0, const float* __restrict__ bias1,
    void* __restrict__ out0, void* __restrict__ out1,
    const int* __restrict__ lab,
    int M, int N0, int N1, int K, int doRelu, int f32o0, int f32o1)
{
    __shared__ ushort_t As[2][4096];
    __shared__ ushort_t Bs[2][4096];
    int N = blockIdx.z ? N1 : N0;
    int tileN = blockIdx.y * 64;
    if (tileN >= N) return;
    const ushort_t* A   = blockIdx.z ? A1 : A0;
    const ushort_t* Bt  = blockIdx.z ? Bt1 : Bt0;
    const float*   bias = blockIdx.z ? bias1 : bias0;
    int           f32o  = blockIdx.z ? f32o1 : f32o0;
    ushort_t*      outH = (ushort_t*)(blockIdx.z ? out1 : out0);
    float*         outF = (float*)(blockIdx.z ? out1 : out0);

    int t = threadIdx.x;
    int lane = t & 63, wave = t >> 6;
    int tileM = blockIdx.x * 64;
    int wm = (wave >> 1) * 32, wn = (wave & 1) * 32;
    int l15 = lane & 15, quad = lane >> 4;

    // staging: per wave, 2 calls/matrix; call c covers LDS rows
    // wave*16 + c*8 + (lane>>3), phys slot lane&7 (lane*16B pattern).
    int grow  = wave * 16 + (lane >> 3);
    int gseg8 = ((lane & 7) ^ (lane >> 3)) << 3;           // ushort offset
    const ushort_t* pA0 = A  + (size_t)(tileM + grow) * K + gseg8;
    const ushort_t* pA1 = A  + (size_t)(tileM + grow + 8) * K + gseg8;
    const ushort_t* pB0 = Bt + (size_t)(tileN + grow) * K + gseg8;
    const ushort_t* pB1 = Bt + (size_t)(tileN + grow + 8) * K + gseg8;
    int ld0 = wave * 1024 + lane * 8;                      // ushort offsets
    int ld1 = ld0 + 512;                                   // +8 rows

    // swizzled ds_read offsets: row*64 + ((ks*4+quad)^(row&7))*8 ushorts
    int offA[2][2], offB[2][2];
#pragma unroll
    for (int mi = 0; mi < 2; ++mi) {
        int rw = wm + mi * 16 + l15;
#pragma unroll
        for (int ks = 0; ks < 2; ++ks)
            offA[mi][ks] = rw * 64 + (((ks * 4 + quad) ^ (rw & 7)) << 3);
    }
#pragma unroll
    for (int ni = 0; ni < 2; ++ni) {
        int rw = wn + ni * 16 + l15;
#pragma unroll
        for (int ks = 0; ks < 2; ++ks)
            offB[ni][ks] = rw * 64 + (((ks * 4 + quad) ^ (rw & 7)) << 3);
    }

    f32x4 acc[2][2];
#pragma unroll
    for (int a = 0; a < 2; ++a)
#pragma unroll
        for (int b = 0; b < 2; ++b) {
            acc[a][b][0] = 0.f; acc[a][b][1] = 0.f;
            acc[a][b][2] = 0.f; acc[a][b][3] = 0.f;
        }

    // prologue: stage tile 0 into buffer 0
    GLL16(pA0, &As[0][ld0]); GLL16(pA1, &As[0][ld1]);
    GLL16(pB0, &Bs[0][ld0]); GLL16(pB1, &Bs[0][ld1]);
    __syncthreads();

    int nk = K >> 6;
    for (int kt = 0; kt < nk; ++kt) {
        int cur = kt & 1;
        if (kt + 1 < nk) {                   // issue next-tile stage early
            int ko = (kt + 1) << 6;
            GLL16(pA0 + ko, &As[cur ^ 1][ld0]);
            GLL16(pA1 + ko, &As[cur ^ 1][ld1]);
            GLL16(pB0 + ko, &Bs[cur ^ 1][ld0]);
            GLL16(pB1 + ko, &Bs[cur ^ 1][ld1]);
        }
        bf16x8 a0k0 = *reinterpret_cast<const bf16x8*>(&As[cur][offA[0][0]]);
        bf16x8 a1k0 = *reinterpret_cast<const bf16x8*>(&As[cur][offA[1][0]]);
        bf16x8 b0k0 = *reinterpret_cast<const bf16x8*>(&Bs[cur][offB[0][0]]);
        bf16x8 b1k0 = *reinterpret_cast<const bf16x8*>(&Bs[cur][offB[1][0]]);
        bf16x8 a0k1 = *reinterpret_cast<const bf16x8*>(&As[cur][offA[0][1]]);
        bf16x8 a1k1 = *reinterpret_cast<const bf16x8*>(&As[cur][offA[1][1]]);
        bf16x8 b0k1 = *reinterpret_cast<const bf16x8*>(&Bs[cur][offB[0][1]]);
        bf16x8 b1k1 = *reinterpret_cast<const bf16x8*>(&Bs[cur][offB[1][1]]);
        acc[0][0] = __builtin_amdgcn_mfma_f32_16x16x32_bf16(a0k0, b0k0, acc[0][0], 0, 0, 0);
        acc[0][1] = __builtin_amdgcn_mfma_f32_16x16x32_bf16(a0k0, b1k0, acc[0][1], 0, 0, 0);
        acc[1][0] = __builtin_amdgcn_mfma_f32_16x16x32_bf16(a1k0, b0k0, acc[1][0], 0, 0, 0);
        acc[1][1] = __builtin_amdgcn_mfma_f32_16x16x32_bf16(a1k0, b1k0, acc[1][1], 0, 0, 0);
        acc[0][0] = __builtin_amdgcn_mfma_f32_16x16x32_bf16(a0k1, b0k1, acc[0][0], 0, 0, 0);
        acc[0][1] = __builtin_amdgcn_mfma_f32_16x16x32_bf16(a0k1, b1k1, acc[0][1], 0, 0, 0);
        acc[1][0] = __builtin_amdgcn_mfma_f32_16x16x32_bf16(a1k1, b0k1, acc[1][0], 0, 0, 0);
        acc[1][1] = __builtin_amdgcn_mfma_f32_16x16x32_bf16(a1k1, b1k1, acc[1][1], 0, 0, 0);
        __syncthreads();                     // drains vmcnt+lgkmcnt: next tile
    }                                        // ready, current buffer consumed

#pragma unroll
    for (int mi = 0; mi < 2; ++mi) {
        int gr = tileM + wm + mi * 16 + quad * 4;
        int lb4[4];
        if (lab) {
#pragma unroll
            for (int r = 0; r < 4; ++r) lb4[r] = lab[gr + r];
        }
#pragma unroll
        for (int ni = 0; ni < 2; ++ni) {
            int gc = tileN + wn + ni * 16 + l15;
            if (gc < N) {
#pragma unroll
                for (int r = 0; r < 4; ++r) {
                    float bb = lab ? bias[(size_t)lb4[r] * N + gc]
                                   : (bias ? bias[gc] : 0.0f);
                    float v = acc[mi][ni][r] + bb;
                    if (doRelu) v = fmaxf(v, 0.0f);
                    if (f32o) outF[(size_t)(gr + r) * N + gc] = v;
                    else      outH[(size_t)(gr + r) * N + gc] = f2b(v);
                }
            }
        }
    }
}

// ---------------------------------------------------------------------------
// Per-relation: logits + log-softmax + loss. One wave per 8 relations.
// Tail-linear term precomputed per ENTITY (tLin, f32).
// ---------------------------------------------------------------------------
__global__ __launch_bounds__(256) void rel_kernel(
    const ushort_t* __restrict__ Uext, const ushort_t* __restrict__ tailsE,
    const float* __restrict__ tLin, const float* __restrict__ lb,
    const int* __restrict__ rel_head, const int* __restrict__ rel_tail,
    const int* __restrict__ rel_label, float* __restrict__ out)
{
    __shared__ float wsum[4];
    int lane = threadIdx.x & 63, wave = threadIdx.x >> 6;
    float lb0 = lb[0], lb1 = lb[1];
    float lossAcc = 0.0f;
    int base = (blockIdx.x * 4 + wave) * 8;

    for (int q = 0; q < 8; ++q) {
        int rel = base + q;
        int b = rel >> 11;                    // R = 2048
        int h = rel_head[rel], t = rel_tail[rel], lab = rel_label[rel];
        const uint32_t* uh = reinterpret_cast<const uint32_t*>(Uext + (size_t)(b * E_ + h) * 770);
        const uint32_t* tv = reinterpret_cast<const uint32_t*>(tailsE + (size_t)(b * E_ + t) * 384);

        float a0 = 0.f, a1 = 0.f;
#pragma unroll
        for (int j = 0; j < 3; ++j) {
            int i = lane + 64 * j;
            uint32_t tu = tv[i];
            uint32_t u0 = uh[i], u1 = uh[192 + i];
            float tl = bl(tu), th = bh(tu);
            a0 += tl * bl(u0) + th * bh(u0);
            a1 += tl * bl(u1) + th * bh(u1);
        }
#pragma unroll
        for (int d = 1; d < 64; d <<= 1) {
            a0 += __shfl_xor(a0, d);
            a1 += __shfl_xor(a1, d);
        }
        const ushort_t* uhs = reinterpret_cast<const ushort_t*>(uh);
        float2 tp = reinterpret_cast<const float2*>(tLin)[b * E_ + t];
        float l0v = a0 + tp.x + b2f(uhs[768]) + lb0;
        float l1v = a1 + tp.y + b2f(uhs[769]) + lb1;
        if (lane == 0) {
            out[1 + 2 * rel]     = l0v;
            out[1 + 2 * rel + 1] = l1v;
        }
        float m = fmaxf(l0v, l1v);
        float lse = m + logf(expf(l0v - m) + expf(l1v - m));
        lossAcc += lse - (lab ? l1v : l0v);
    }
    if (lane == 0) wsum[wave] = lossAcc;
    __syncthreads();
    if (threadIdx.x == 0) {
        float s = wsum[0] + wsum[1] + wsum[2] + wsum[3];
        atomicAdd(out, s * (1.0f / 32768.0f));
    }
}

// ---------------------------------------------------------------------------
extern "C" void kernel_launch(void* const* d_in, const int* in_sizes, int n_in,
                              void* d_out, int out_size, void* d_ws, size_t ws_size,
                              hipStream_t stream)
{
    const float* hidden = (const float*)d_in[0];
    const float* emb    = (const float*)d_in[1];
    const float* hW1    = (const float*)d_in[2];
    const float* hb1    = (const float*)d_in[3];
    const float* hW2    = (const float*)d_in[4];
    const float* hb2    = (const float*)d_in[5];
    const float* tW1    = (const float*)d_in[6];
    const float* tb1    = (const float*)d_in[7];
    const float* tW2    = (const float*)d_in[8];
    const float* tb2    = (const float*)d_in[9];
    const float* bil    = (const float*)d_in[10];
    const float* lW     = (const float*)d_in[11];
    const float* lb     = (const float*)d_in[12];
    const int* ent_start = (const int*)d_in[13];
    const int* ent_label = (const int*)d_in[14];
    const int* rel_head  = (const int*)d_in[15];
    const int* rel_tail  = (const int*)d_in[16];
    const int* rel_label = (const int*)d_in[17];
    float* out = (float*)d_out;

    char* ws = (char*)d_ws;
    ushort_t* repE   = (ushort_t*)(ws + 0);         // [2048,768]
    ushort_t* hW1T   = (ushort_t*)(ws + 3145728);   // [768,768]  (top half only)
    ushort_t* tW1T   = (ushort_t*)(ws + 4325376);   // [768,768]
    ushort_t* hW2T   = (ushort_t*)(ws + 5505024);   // [384,768]
    ushort_t* tW2T   = (ushort_t*)(ws + 6094848);   // [384,768]
    ushort_t* BmatT  = (ushort_t*)(ws + 6684672);   // [770,384]
    ushort_t* lWtT   = (ushort_t*)(ws + 7276032);   // [2,384]
    float*    biasEh = (float*)   (ws + 7277568);   // [3,768] f32
    float*    biasEt = (float*)   (ws + 7286784);   // [3,768] f32
    float*    tLin   = (float*)   (ws + 7296000);   // [2048,2] f32
    ushort_t* h1     = (ushort_t*)(ws + 7312384);   // [2048,768]
    ushort_t* t1     = (ushort_t*)(ws + 10458112);  // [2048,768]
    ushort_t* headsE = (ushort_t*)(ws + 13603840);  // [2048,384]
    ushort_t* tailsE = (ushort_t*)(ws + 15176704);  // [2048,384]
    ushort_t* Uext   = (ushort_t*)(ws + 16749568);  // [2048,770]

    prep_fused<<<3582, 256, 0, stream>>>(
        hidden, emb, lW, hW1, tW1, hW2, tW2, bil, hb1, tb1, ent_start,
        repE, hW1T, tW1T, hW2T, tW2T, BmatT, lWtT, biasEh, biasEt, out);

    // tower-1: h1/t1 = relu(hid @ W1_top + biasE[lab])   (K=768)
    gemm_lds<<<dim3(32, 12, 2), 256, 0, stream>>>(
        repE, repE, hW1T, tW1T, biasEh, biasEt, h1, t1, ent_label,
        2048, 768, 768, 768, 1, 0, 0);

    // tower-2: heads/tails = relu(h @ W2 + b2)
    gemm_lds<<<dim3(32, 6, 2), 256, 0, stream>>>(
        h1, t1, hW2T, tW2T, hb2, tb2, headsE, tailsE, nullptr,
        2048, 384, 384, 768, 1, 0, 0);

    // z=0: Uext = heads @ [bil0^T | bil1^T | lW_head]  (bf16)
    // z=1: tLin = tails @ lW_tail^T                    (f32, [2048,2])
    gemm_lds<<<dim3(32, 13, 2), 256, 0, stream>>>(
        headsE, tailsE, BmatT, lWtT, nullptr, nullptr, Uext, tLin, nullptr,
        2048, 770, 2, 384, 0, 0, 1);

    rel_kernel<<<1024, 256, 0, stream>>>(
        Uext, tailsE, tLin, lb, rel_head, rel_tail, rel_label, out);
}